// Round 1
// baseline (226.610 us; speedup 1.0000x reference)
//
#include <hip/hip_runtime.h>

#define WAVE 64

// Compute s = (x + OFFSETS[argmin_o dist(euc_xt, cell@(x+off_o))]) - x_tilde  for atom n.
__device__ __forceinline__ void compute_s(const float c[9],
                                          const float* __restrict__ x,
                                          const float* __restrict__ xt,
                                          int n, float& s0, float& s1, float& s2) {
  const float x0 = x[3 * n + 0], x1 = x[3 * n + 1], x2 = x[3 * n + 2];
  const float t0 = xt[3 * n + 0], t1 = xt[3 * n + 1], t2 = xt[3 * n + 2];
  // euc_x_tilde = cell @ x_tilde
  const float e0 = c[0] * t0 + c[1] * t1 + c[2] * t2;
  const float e1 = c[3] * t0 + c[4] * t1 + c[5] * t2;
  const float e2 = c[6] * t0 + c[7] * t1 + c[8] * t2;
  float best = 3.4e38f;
  int bo = 0;
#pragma unroll
  for (int o = 0; o < 27; ++o) {
    const float f0 = x0 + (float)(o / 9 - 1);
    const float f1 = x1 + (float)((o / 3) % 3 - 1);
    const float f2 = x2 + (float)(o % 3 - 1);
    const float u0 = c[0] * f0 + c[1] * f1 + c[2] * f2;
    const float u1 = c[3] * f0 + c[4] * f1 + c[5] * f2;
    const float u2 = c[6] * f0 + c[7] * f1 + c[8] * f2;
    const float d0 = e0 - u0, d1 = e1 - u1, d2 = e2 - u2;
    const float d = d0 * d0 + d1 * d1 + d2 * d2;
    if (d < best) { best = d; bo = o; }  // strict < => first-min tie-break like jnp.argmin
  }
  s0 = x0 + (float)(bo / 9 - 1) - t0;
  s1 = x1 + (float)((bo / 3) % 3 - 1) - t1;
  s2 = x2 + (float)(bo % 3 - 1) - t2;
}

__device__ __forceinline__ float wave_sum(float v) {
#pragma unroll
  for (int m = 32; m >= 1; m >>= 1) v += __shfl_xor(v, m);
  return v;
}

// One 64-lane wave per structure.
__global__ __launch_bounds__(WAVE) void mdl_main(const float* __restrict__ cell,
                                                 const float* __restrict__ x,
                                                 const float* __restrict__ xt,
                                                 const int* __restrict__ na,
                                                 const int* __restrict__ starts,
                                                 double* __restrict__ acc) {
  const int b = blockIdx.x;
  const int tid = threadIdx.x;
  const int start = starts[b];
  const int count = na[b];

  float c[9];
#pragma unroll
  for (int i = 0; i < 9; ++i) c[i] = cell[9 * b + i];

  float sumx = 0.f, sumy = 0.f, sumz = 0.f;
  float s0 = 0.f, s1 = 0.f, s2 = 0.f;
  bool have = false;

  if (count <= WAVE) {
    // fast path: one atom per lane, s stays in registers
    if (tid < count) {
      compute_s(c, x, xt, start + tid, s0, s1, s2);
      have = true;
      sumx = s0; sumy = s1; sumz = s2;
    }
  } else {
    for (int n = start + tid; n < start + count; n += WAVE) {
      float a0, a1, a2;
      compute_s(c, x, xt, n, a0, a1, a2);
      sumx += a0; sumy += a1; sumz += a2;
    }
  }

  sumx = wave_sum(sumx); sumy = wave_sum(sumy); sumz = wave_sum(sumz);
  const float inv = 1.0f / (float)count;
  const float cx = sumx * inv, cy = sumy * inv, cz = sumz * inv;

  float part = 0.f;
  if (count <= WAVE) {
    if (have) part = fabsf(cx - s0) + fabsf(cy - s1) + fabsf(cz - s2);
  } else {
    for (int n = start + tid; n < start + count; n += WAVE) {
      float a0, a1, a2;
      compute_s(c, x, xt, n, a0, a1, a2);  // recompute path (general num_atoms)
      part += fabsf(cx - a0) + fabsf(cy - a1) + fabsf(cz - a2);
    }
  }
  part = wave_sum(part);
  if (tid == 0) atomicAdd(acc, (double)part);
}

// Exclusive prefix sum of num_atoms -> starts[0..B-1]; also zeroes the accumulator.
__global__ void mdl_scan(const int* __restrict__ na, int* __restrict__ starts, int B,
                         double* __restrict__ acc) {
  __shared__ int part[1024];
  const int tid = threadIdx.x;
  if (tid == 0) *acc = 0.0;
  const int chunk = (B + 1023) / 1024;
  const int lo = min(tid * chunk, B);
  const int hi = min(lo + chunk, B);
  int s = 0;
  for (int i = lo; i < hi; ++i) s += na[i];
  part[tid] = s;
  __syncthreads();
  for (int off = 1; off < 1024; off <<= 1) {
    int v = 0;
    if (tid >= off) v = part[tid - off];
    __syncthreads();
    if (tid >= off) part[tid] += v;
    __syncthreads();
  }
  int ex = (tid == 0) ? 0 : part[tid - 1];
  for (int i = lo; i < hi; ++i) { starts[i] = ex; ex += na[i]; }
}

__global__ void mdl_final(const double* __restrict__ acc, float* __restrict__ out, int N) {
  out[0] = (float)(acc[0] / (3.0 * (double)N));
}

extern "C" void kernel_launch(void* const* d_in, const int* in_sizes, int n_in,
                              void* d_out, int out_size, void* d_ws, size_t ws_size,
                              hipStream_t stream) {
  const float* cell = (const float*)d_in[0];
  const float* x    = (const float*)d_in[1];
  const float* xt   = (const float*)d_in[2];
  const int*   na   = (const int*)d_in[3];
  const int B = in_sizes[3];
  const int N = in_sizes[1] / 3;

  double* acc = (double*)d_ws;
  int* starts = (int*)((char*)d_ws + 64);

  mdl_scan<<<1, 1024, 0, stream>>>(na, starts, B, acc);
  mdl_main<<<B, WAVE, 0, stream>>>(cell, x, xt, na, starts, acc);
  mdl_final<<<1, 1, 0, stream>>>(acc, (float*)d_out, N);
}

// Round 2
// 39.884 us; speedup vs baseline: 5.6817x; 5.6817x over previous
//
#include <hip/hip_runtime.h>

#define WAVE 64
#define WAVES_PER_BLOCK 4
#define BLOCK (WAVE * WAVES_PER_BLOCK)

// s = (x + OFFSETS[argmin_o |euc_xt - cell@(x+off_o)|]) - x_tilde  for atom n.
// Incremental form: r = cell@(x_tilde - x); d_o = r - (dx*col0 + dy*col1 + dz*col2).
__device__ __forceinline__ void compute_s(const float c[9],
                                          const float* __restrict__ x,
                                          const float* __restrict__ xt,
                                          int n, float& s0, float& s1, float& s2) {
  const float x0 = x[3 * n + 0], x1 = x[3 * n + 1], x2 = x[3 * n + 2];
  const float t0 = xt[3 * n + 0], t1 = xt[3 * n + 1], t2 = xt[3 * n + 2];
  // euc_xt = cell @ t ; base = cell @ x ; r = euc_xt - base (match ref rounding:
  // ref computes e - u where both are full matvecs; difference-of-matvecs vs
  // matvec-of-difference differ only in ulps, threshold is 7.9e-4)
  const float e0 = c[0] * t0 + c[1] * t1 + c[2] * t2;
  const float e1 = c[3] * t0 + c[4] * t1 + c[5] * t2;
  const float e2 = c[6] * t0 + c[7] * t1 + c[8] * t2;
  const float b0 = c[0] * x0 + c[1] * x1 + c[2] * x2;
  const float b1 = c[3] * x0 + c[4] * x1 + c[5] * x2;
  const float b2 = c[6] * x0 + c[7] * x1 + c[8] * x2;
  const float r0 = e0 - b0, r1 = e1 - b1, r2 = e2 - b2;

  float best = 3.4e38f;
  int bo = 0;
#pragma unroll
  for (int i = 0; i < 3; ++i) {
    const float di = (float)(i - 1);
    const float p0 = r0 - di * c[0], p1 = r1 - di * c[3], p2 = r2 - di * c[6];
#pragma unroll
    for (int j = 0; j < 3; ++j) {
      const float dj = (float)(j - 1);
      const float q0 = p0 - dj * c[1], q1 = p1 - dj * c[4], q2 = p2 - dj * c[7];
#pragma unroll
      for (int k = 0; k < 3; ++k) {
        const float dk = (float)(k - 1);
        const float u0 = q0 - dk * c[2], u1 = q1 - dk * c[5], u2 = q2 - dk * c[8];
        const float d = u0 * u0 + u1 * u1 + u2 * u2;
        const int o = 9 * i + 3 * j + k;
        if (d < best) { best = d; bo = o; }  // strict < => first-min, like jnp.argmin
      }
    }
  }
  s0 = x0 + (float)(bo / 9 - 1) - t0;
  s1 = x1 + (float)((bo / 3) % 3 - 1) - t1;
  s2 = x2 + (float)(bo % 3 - 1) - t2;
}

__device__ __forceinline__ float wave_sum(float v) {
#pragma unroll
  for (int m = 32; m >= 1; m >>= 1) v += __shfl_xor(v, m);
  return v;
}

// 4 waves per block, one structure per wave. Block writes ONE partial (no atomics).
__global__ __launch_bounds__(BLOCK) void mdl_main(const float* __restrict__ cell,
                                                  const float* __restrict__ x,
                                                  const float* __restrict__ xt,
                                                  const int* __restrict__ na,
                                                  const int* __restrict__ starts,
                                                  float* __restrict__ partial, int B) {
  __shared__ float wpart[WAVES_PER_BLOCK];
  const int wid = threadIdx.x / WAVE;
  const int tid = threadIdx.x % WAVE;
  const int b = blockIdx.x * WAVES_PER_BLOCK + wid;

  float part = 0.f;
  if (b < B) {
    const int start = starts[b];
    const int count = na[b];

    float c[9];
#pragma unroll
    for (int i = 0; i < 9; ++i) c[i] = cell[9 * b + i];

    float sumx = 0.f, sumy = 0.f, sumz = 0.f;
    float s0 = 0.f, s1 = 0.f, s2 = 0.f;
    bool have = false;

    if (count <= WAVE) {
      if (tid < count) {
        compute_s(c, x, xt, start + tid, s0, s1, s2);
        have = true;
        sumx = s0; sumy = s1; sumz = s2;
      }
    } else {
      for (int n = start + tid; n < start + count; n += WAVE) {
        float a0, a1, a2;
        compute_s(c, x, xt, n, a0, a1, a2);
        sumx += a0; sumy += a1; sumz += a2;
      }
    }

    sumx = wave_sum(sumx); sumy = wave_sum(sumy); sumz = wave_sum(sumz);
    const float inv = 1.0f / (float)count;
    const float cx = sumx * inv, cy = sumy * inv, cz = sumz * inv;

    if (count <= WAVE) {
      if (have) part = fabsf(cx - s0) + fabsf(cy - s1) + fabsf(cz - s2);
    } else {
      for (int n = start + tid; n < start + count; n += WAVE) {
        float a0, a1, a2;
        compute_s(c, x, xt, n, a0, a1, a2);
        part += fabsf(cx - a0) + fabsf(cy - a1) + fabsf(cz - a2);
      }
    }
    part = wave_sum(part);
  }

  if (tid == 0) wpart[wid] = part;
  __syncthreads();
  if (threadIdx.x == 0) {
    float s = 0.f;
#pragma unroll
    for (int w = 0; w < WAVES_PER_BLOCK; ++w) s += wpart[w];
    partial[blockIdx.x] = s;
  }
}

// Exclusive prefix sum of num_atoms -> starts[0..B-1].
__global__ void mdl_scan(const int* __restrict__ na, int* __restrict__ starts, int B) {
  __shared__ int part[1024];
  const int tid = threadIdx.x;
  const int chunk = (B + 1023) / 1024;
  const int lo = min(tid * chunk, B);
  const int hi = min(lo + chunk, B);
  int s = 0;
  for (int i = lo; i < hi; ++i) s += na[i];
  part[tid] = s;
  __syncthreads();
  for (int off = 1; off < 1024; off <<= 1) {
    int v = 0;
    if (tid >= off) v = part[tid - off];
    __syncthreads();
    if (tid >= off) part[tid] += v;
    __syncthreads();
  }
  int ex = (tid == 0) ? 0 : part[tid - 1];
  for (int i = lo; i < hi; ++i) { starts[i] = ex; ex += na[i]; }
}

// Sum nparts floats (double accum) -> out = sum / (3*N).
__global__ __launch_bounds__(1024) void mdl_final(const float* __restrict__ partial,
                                                  int nparts, float* __restrict__ out,
                                                  int N) {
  __shared__ double wsum[16];
  double s = 0.0;
  for (int i = threadIdx.x; i < nparts; i += 1024) s += (double)partial[i];
#pragma unroll
  for (int m = 32; m >= 1; m >>= 1) s += __shfl_xor(s, m);
  if ((threadIdx.x & (WAVE - 1)) == 0) wsum[threadIdx.x / WAVE] = s;
  __syncthreads();
  if (threadIdx.x == 0) {
    double t = 0.0;
#pragma unroll
    for (int w = 0; w < 16; ++w) t += wsum[w];
    out[0] = (float)(t / (3.0 * (double)N));
  }
}

extern "C" void kernel_launch(void* const* d_in, const int* in_sizes, int n_in,
                              void* d_out, int out_size, void* d_ws, size_t ws_size,
                              hipStream_t stream) {
  const float* cell = (const float*)d_in[0];
  const float* x    = (const float*)d_in[1];
  const float* xt   = (const float*)d_in[2];
  const int*   na   = (const int*)d_in[3];
  const int B = in_sizes[3];
  const int N = in_sizes[1] / 3;

  const int nblocks = (B + WAVES_PER_BLOCK - 1) / WAVES_PER_BLOCK;
  float* partial = (float*)d_ws;                          // nblocks floats
  int* starts = (int*)((char*)d_ws + ((size_t)nblocks * 4 + 255 & ~255ULL));

  mdl_scan<<<1, 1024, 0, stream>>>(na, starts, B);
  mdl_main<<<nblocks, BLOCK, 0, stream>>>(cell, x, xt, na, starts, partial, B);
  mdl_final<<<1, 1024, 0, stream>>>(partial, nblocks, (float*)d_out, N);
}